// Round 8
// baseline (5286.653 us; speedup 1.0000x reference)
//
#include <hip/hip_runtime.h>
#include <stdint.h>

// LSTMClassifier on MI355X — round 8: sentinel data-polling scan.
// Round 7 (counter + barrier-drained coherent stores) = 6.9 us/step: the
// critical path was ~4 fabric round-trips (store drain, fetch_add, counter
// poll, h load). This round merges readiness+data into ONE mechanism:
// hbuf[1..] prefilled with 0x7F bytes (bf16 0x7F7F = 3.4e38, impossible for
// |h|<=1); producers fire-and-forget coherent u32 h-stores (no barrier, no
// counter); consumers re-load any u32 still reading sentinel. One
// __syncthreads per step (gates LDS double-buffered); c-state in registers.
//
// Workspace (48.2 MiB):
//   [4096, +33.6MB)  bf16 h_buf[513][64][512]  (step0 memset 0, rest 0x7F)
//   [+,   +16.8MB)   bf16 e_seq[32768][256]

#define EMB   256
#define HID   512
#define NOUT  18
#define BATCH 64
#define SEQ   512

typedef __attribute__((ext_vector_type(8))) short bf16x8;
typedef __attribute__((ext_vector_type(4))) float floatx4;

__device__ inline float bf2f(short u) {
    union { float f; uint32_t i; } v;
    v.i = ((uint32_t)(uint16_t)u) << 16;
    return v.f;
}
__device__ inline short f2bf(float f) {
    union { float f; uint32_t i; } v; v.f = f;
    uint32_t r = v.i + 0x7fffu + ((v.i >> 16) & 1u);   // RNE
    return (short)(r >> 16);
}
__device__ inline float sigm(float x) { return 1.f / (1.f + __expf(-x)); }
__device__ inline float tanh_fast(float x) {
    float xc = fminf(fmaxf(x, -15.f), 15.f);
    float e  = __expf(2.f * xc);
    return (e - 1.f) / (e + 1.f);
}

// u64 contains a not-yet-written u32 half? (producer writes whole u32s)
__device__ inline bool hassent(unsigned long long v) {
    return ((uint32_t)v == 0x7F7F7F7Fu) || ((uint32_t)(v >> 32) == 0x7F7F7F7Fu);
}

// Detect packed-bf16 vs fp32 float tensors (verified round 4 — keep).
__device__ inline bool detect_bf16(const void* emb_raw) {
    const uint32_t* w = (const uint32_t*)emb_raw;
    int votes = 0;
    #pragma unroll
    for (int i = 0; i < 8; i++) {
        uint32_t e = (w[i] >> 7) & 0xFFu;
        votes += (e >= 110u && e <= 135u) ? 1 : 0;
    }
    return votes >= 6;
}
__device__ inline float rd(const void* p, int idx, bool isbf) {
    return isbf ? bf2f(((const short*)p)[idx]) : ((const float*)p)[idx];
}

// ---------------------------------------------------------------------------
// K0: e_seq[u][k] = emb[x[u&63][u>>6]][k] (bf16 out), u = s*64+b.
// ---------------------------------------------------------------------------
__global__ __launch_bounds__(256) void k0_gather(
    const int* __restrict__ x, const void* __restrict__ emb,
    short* __restrict__ eseq)
{
    const bool isbf = detect_bf16(emb);
    const int u0 = blockIdx.x * 32;
    #pragma unroll
    for (int it = 0; it < 4; it++) {
        int idx = it * 256 + threadIdx.x;          // 0..1023
        int u   = u0 + (idx >> 5);
        int ch  = (idx & 31) * 8;
        int tok = x[(u & 63) * SEQ + (u >> 6)];
        bf16x8 v;
        if (isbf) {
            v = *(const bf16x8*)((const short*)emb + (size_t)tok * EMB + ch);
        } else {
            const float* src = (const float*)emb + (size_t)tok * EMB + ch;
            #pragma unroll
            for (int j = 0; j < 8; j++) v[j] = f2bf(src[j]);
        }
        *(bf16x8*)(eseq + (size_t)u * EMB + ch) = v;
    }
}

// ---------------------------------------------------------------------------
// K2: persistent LSTM scan, sentinel-polled h exchange. 64 wgs; wg g owns
// h/gate columns [8g, 8g+8). LDS Ws row n (q=n>>3, j=n&7): cols [0,512)=
// W_hh row q*512+g*8+j, cols [512,768)=W_ih same row. Staged ONCE.
// ---------------------------------------------------------------------------
__global__ __launch_bounds__(256) void k2_lstm(
    const void* __restrict__ w_hh, const void* __restrict__ w_ih,
    const void* __restrict__ b_ih, const void* __restrict__ b_hh,
    const void* __restrict__ emb, const short* __restrict__ eseq,
    short* __restrict__ hbuf)
{
    __shared__ short Ws[32][784];        // 768 + 16 pad, 49 KB
    __shared__ float gates[2][64][33];   // double-buffered, 2 x 8.25 KB
    __shared__ float biasl[32];

    const bool isbf = detect_bf16(emb);
    const int t    = threadIdx.x;
    const int g    = blockIdx.x;      // 0..63
    const int lane = t & 63;
    const int w    = t >> 6;
    const int col  = lane & 15;
    const int quad = lane >> 4;

    // ---- one-time staging ----
    #pragma unroll
    for (int it = 0; it < 8; it++) {                 // W_hh slice 32x512
        int idx = it * 256 + t;
        int n = idx >> 6, ch = (idx & 63) * 8;
        int grow = (n >> 3) * HID + g * 8 + (n & 7);
        bf16x8 v;
        if (isbf) {
            v = *(const bf16x8*)((const short*)w_hh + (size_t)grow * HID + ch);
        } else {
            const float* src = (const float*)w_hh + (size_t)grow * HID + ch;
            #pragma unroll
            for (int j = 0; j < 8; j++) v[j] = f2bf(src[j]);
        }
        *(bf16x8*)&Ws[n][ch] = v;
    }
    #pragma unroll
    for (int it = 0; it < 4; it++) {                 // W_ih slice 32x256
        int idx = it * 256 + t;
        int n = idx >> 5, ch = (idx & 31) * 8;
        int grow = (n >> 3) * HID + g * 8 + (n & 7);
        bf16x8 v;
        if (isbf) {
            v = *(const bf16x8*)((const short*)w_ih + (size_t)grow * EMB + ch);
        } else {
            const float* src = (const float*)w_ih + (size_t)grow * EMB + ch;
            #pragma unroll
            for (int j = 0; j < 8; j++) v[j] = f2bf(src[j]);
        }
        *(bf16x8*)&Ws[n][HID + ch] = v;
    }
    if (t < 32) {
        int grow = (t >> 3) * HID + g * 8 + (t & 7);
        biasl[t] = rd(b_ih, grow, isbf) + rd(b_hh, grow, isbf);
    }
    __syncthreads();

    // per-thread cell state + biases in registers (mapping m=t>>2, j0=2(t&3))
    const int m  = t >> 2;
    const int j0 = (t & 3) * 2;
    const int j1 = j0 + 1;
    float c0r = 0.f, c1r = 0.f;
    const float bi0 = biasl[j0],      bi1 = biasl[j1];
    const float bf0 = biasl[8 + j0],  bf1 = biasl[8 + j1];
    const float bg0 = biasl[16 + j0], bg1 = biasl[16 + j1];
    const float bo0 = biasl[24 + j0], bo1 = biasl[24 + j1];

    const unsigned long long* hq = (const unsigned long long*)hbuf;
    const size_t arow = (size_t)(w * 16 + col) * HID + quad * 8;   // short idx

    // ---- scan ----
    for (int step = 0; step < SEQ; step++) {
        // poll-load A fragments: h chunks via coherent u64 loads, retry while
        // sentinel (0x7F7F7F7F per producer u32). Readiness == data arrival.
        const unsigned long long* hqp =
            hq + (((size_t)step * (BATCH * HID) + arow) >> 2);
        unsigned long long qv[32];
        #pragma unroll
        for (int kk = 0; kk < 16; kk++) {
            qv[2 * kk]     = __hip_atomic_load(hqp + kk * 8,
                                 __ATOMIC_RELAXED, __HIP_MEMORY_SCOPE_AGENT);
            qv[2 * kk + 1] = __hip_atomic_load(hqp + kk * 8 + 1,
                                 __ATOMIC_RELAXED, __HIP_MEMORY_SCOPE_AGENT);
        }
        #pragma unroll
        for (int i = 0; i < 32; i++) {
            while (__builtin_expect(hassent(qv[i]), 0))
                qv[i] = __hip_atomic_load(hqp + (i >> 1) * 8 + (i & 1),
                            __ATOMIC_RELAXED, __HIP_MEMORY_SCOPE_AGENT);
        }

        bf16x8 afr[24];
        #pragma unroll
        for (int kk = 0; kk < 16; kk++) {
            union { bf16x8 v; unsigned long long q[2]; } u;
            u.q[0] = qv[2 * kk]; u.q[1] = qv[2 * kk + 1];
            afr[kk] = u.v;
        }
        {
            const short* erow = eseq + ((size_t)step * BATCH + (w * 16 + col)) * EMB
                              + quad * 8;
            #pragma unroll
            for (int kk = 0; kk < 8; kk++)
                afr[16 + kk] = *(const bf16x8*)(erow + kk * 32);
        }

        floatx4 acc0 = (floatx4){0.f, 0.f, 0.f, 0.f};
        floatx4 acc1 = (floatx4){0.f, 0.f, 0.f, 0.f};
        #pragma unroll
        for (int kk = 0; kk < 24; kk++) {
            bf16x8 b0 = *(bf16x8*)&Ws[col][kk * 32 + quad * 8];
            bf16x8 b1 = *(bf16x8*)&Ws[16 + col][kk * 32 + quad * 8];
            acc0 = __builtin_amdgcn_mfma_f32_16x16x32_bf16(afr[kk], b0, acc0, 0, 0, 0);
            acc1 = __builtin_amdgcn_mfma_f32_16x16x32_bf16(afr[kk], b1, acc1, 0, 0, 0);
        }
        const int buf = step & 1;
        #pragma unroll
        for (int r = 0; r < 4; r++) {
            gates[buf][w * 16 + quad * 4 + r][col]      = acc0[r];
            gates[buf][w * 16 + quad * 4 + r][16 + col] = acc1[r];
        }
        __syncthreads();   // the ONLY per-step barrier (gates cross-wave)

        // postprocess own pair; fire-and-forget coherent u32 store
        {
            float iv0 = sigm(gates[buf][m][j0]      + bi0);
            float fv0 = sigm(gates[buf][m][8 + j0]  + bf0);
            float gv0 = tanh_fast(gates[buf][m][16 + j0] + bg0);
            float ov0 = sigm(gates[buf][m][24 + j0] + bo0);
            float iv1 = sigm(gates[buf][m][j1]      + bi1);
            float fv1 = sigm(gates[buf][m][8 + j1]  + bf1);
            float gv1 = tanh_fast(gates[buf][m][16 + j1] + bg1);
            float ov1 = sigm(gates[buf][m][24 + j1] + bo1);
            c0r = fv0 * c0r + iv0 * gv0;
            c1r = fv1 * c1r + iv1 * gv1;
            float h0 = ov0 * tanh_fast(c0r);
            float h1 = ov1 * tanh_fast(c1r);
            uint32_t pack = (uint32_t)(uint16_t)f2bf(h0)
                          | ((uint32_t)(uint16_t)f2bf(h1) << 16);
            size_t widx = ((size_t)(step + 1) * (BATCH * HID)
                         + (size_t)m * HID + g * 8 + j0) >> 1;
            __hip_atomic_store((uint32_t*)hbuf + widx, pack,
                               __ATOMIC_RELAXED, __HIP_MEMORY_SCOPE_AGENT);
        }
        // no barrier, no counter: consumers detect arrival via sentinel.
    }
}

// ---------------------------------------------------------------------------
// K3: logits = h_seq * W_fc^T + b_fc -> log_softmax(18). One token per thread.
// ---------------------------------------------------------------------------
__global__ __launch_bounds__(256) void k3_logits(
    const short* __restrict__ hbuf, const void* __restrict__ w_fc,
    const void* __restrict__ b_fc, const void* __restrict__ emb,
    void* __restrict__ out)
{
    __shared__ float Wf[NOUT][516];
    const bool isbf = detect_bf16(emb);
    const int t = threadIdx.x;
    for (int idx = t; idx < NOUT * 64; idx += 256) {
        int o = idx >> 6, ch = (idx & 63) * 8;
        #pragma unroll
        for (int j = 0; j < 8; j++)
            Wf[o][ch + j] = rd(w_fc, o * HID + ch + j, isbf);
    }
    __syncthreads();

    int u = blockIdx.x * 256 + t;              // u = s*64+b
    const short* hp = hbuf + (size_t)(u + BATCH) * HID;

    float acc[NOUT];
    #pragma unroll
    for (int o = 0; o < NOUT; o++) acc[o] = rd(b_fc, o, isbf);

    for (int ch = 0; ch < HID; ch += 8) {
        bf16x8 h8 = *(const bf16x8*)(hp + ch);
        float hf[8];
        #pragma unroll
        for (int j = 0; j < 8; j++) hf[j] = bf2f(h8[j]);
        #pragma unroll
        for (int o = 0; o < NOUT; o++) {
            floatx4 wa = *(const floatx4*)&Wf[o][ch];
            floatx4 wb = *(const floatx4*)&Wf[o][ch + 4];
            acc[o] += hf[0] * wa[0] + hf[1] * wa[1] + hf[2] * wa[2] + hf[3] * wa[3]
                    + hf[4] * wb[0] + hf[5] * wb[1] + hf[6] * wb[2] + hf[7] * wb[3];
        }
    }

    float mx = acc[0];
    #pragma unroll
    for (int o = 1; o < NOUT; o++) mx = fmaxf(mx, acc[o]);
    float s = 0.f;
    #pragma unroll
    for (int o = 0; o < NOUT; o++) s += __expf(acc[o] - mx);
    float lse = mx + __logf(s);

    int b = u & 63, sq = u >> 6;
    size_t base = (size_t)b * (SEQ * NOUT) + (size_t)sq * NOUT;
    if (isbf) {
        short* op = (short*)out + base;
        #pragma unroll
        for (int o = 0; o < NOUT; o++) op[o] = f2bf(acc[o] - lse);
    } else {
        float* op = (float*)out + base;
        #pragma unroll
        for (int o = 0; o < NOUT; o++) op[o] = acc[o] - lse;
    }
}

// ---------------------------------------------------------------------------
extern "C" void kernel_launch(void* const* d_in, const int* in_sizes, int n_in,
                              void* d_out, int out_size, void* d_ws, size_t ws_size,
                              hipStream_t stream) {
    const int*  x   = (const int*)d_in[0];
    const void* emb = d_in[1];
    const void* wih = d_in[2];
    const void* whh = d_in[3];
    const void* bih = d_in[4];
    const void* bhh = d_in[5];
    const void* wfc = d_in[6];
    const void* bfc = d_in[7];

    char*  ws   = (char*)d_ws;
    short* hbuf = (short*)(ws + 4096);
    short* eseq = (short*)(ws + 4096 + (size_t)(SEQ + 1) * BATCH * HID * 2);

    const size_t slab = (size_t)BATCH * HID * 2;                 // 64 KB/step
    (void)hipMemsetAsync(hbuf, 0, slab, stream);                 // h_0 = 0
    (void)hipMemsetAsync((char*)hbuf + slab, 0x7F,
                         (size_t)SEQ * slab, stream);            // sentinel

    k0_gather<<<1024, 256, 0, stream>>>(x, emb, eseq);
    k2_lstm<<<64, 256, 0, stream>>>(whh, wih, bih, bhh, emb, eseq, hbuf);
    k3_logits<<<128, 256, 0, stream>>>(hbuf, wfc, bfc, emb, d_out);
}

// Round 9
// 3215.140 us; speedup vs baseline: 1.6443x; 1.6443x over previous
//
#include <hip/hip_runtime.h>
#include <stdint.h>

// LSTMClassifier on MI355X — round 9: intra-XCD persistent scan.
// Rounds 6-8 showed cross-XCD exchange costs 3.5-7 us/step regardless of
// protocol (fence+flags / counter / sentinel-polling): agent-scope accesses
// bypass XCD L2 (hence FETCH_SIZE 200-490 MB) and pay fabric latency.
// This round places ALL 32 scan workgroups on ONE XCD (leader-claim via
// HW_REG_XCC_ID), making the h exchange local-L2: plain stores (write-through
// L1 -> L2), plain first-touch loads (no stale L1 possible), counter sync via
// atomic RMW (coherent at the execution point in any lowering).
//
// Workspace (50.5 MiB):
//   [0,4096)        int sync[1024]: [0]=leader(0=unset,xcd+1), [8..16)=claim,
//                   [64..577)=cnt[step]   (memset 0 per launch)
//   [4096,+33.6MB)  bf16 h_buf[513][64][512]   (h_buf[0] memset 0)
//   [+,  +16.8MB)   bf16 e_seq[32768][256]

#define EMB   256
#define HID   512
#define NOUT  18
#define BATCH 64
#define SEQ   512
#define NPART 32     // scan workgroups = CUs on one XCD
#define WCOLS 16     // h-cols per wg (512/32)
#define GROWS 64     // gate rows per wg (4*WCOLS)
#define WSROW 776    // Ws row stride (shorts): 768+8 pad, 16B-aligned, 2-way banks

typedef __attribute__((ext_vector_type(8))) short bf16x8;
typedef __attribute__((ext_vector_type(4))) float floatx4;

__device__ inline float bf2f(short u) {
    union { float f; uint32_t i; } v;
    v.i = ((uint32_t)(uint16_t)u) << 16;
    return v.f;
}
__device__ inline short f2bf(float f) {
    union { float f; uint32_t i; } v; v.f = f;
    uint32_t r = v.i + 0x7fffu + ((v.i >> 16) & 1u);   // RNE
    return (short)(r >> 16);
}
__device__ inline float sigm(float x) { return 1.f / (1.f + __expf(-x)); }
__device__ inline float tanh_fast(float x) {
    float xc = fminf(fmaxf(x, -15.f), 15.f);
    float e  = __expf(2.f * xc);
    return (e - 1.f) / (e + 1.f);
}

// Detect packed-bf16 vs fp32 float tensors (verified round 4 — keep).
__device__ inline bool detect_bf16(const void* emb_raw) {
    const uint32_t* w = (const uint32_t*)emb_raw;
    int votes = 0;
    #pragma unroll
    for (int i = 0; i < 8; i++) {
        uint32_t e = (w[i] >> 7) & 0xFFu;
        votes += (e >= 110u && e <= 135u) ? 1 : 0;
    }
    return votes >= 6;
}
__device__ inline float rd(const void* p, int idx, bool isbf) {
    return isbf ? bf2f(((const short*)p)[idx]) : ((const float*)p)[idx];
}

// ---------------------------------------------------------------------------
// K0: e_seq[u][k] = emb[x[u&63][u>>6]][k] (bf16 out), u = s*64+b.
// ---------------------------------------------------------------------------
__global__ __launch_bounds__(256) void k0_gather(
    const int* __restrict__ x, const void* __restrict__ emb,
    short* __restrict__ eseq)
{
    const bool isbf = detect_bf16(emb);
    const int u0 = blockIdx.x * 32;
    #pragma unroll
    for (int it = 0; it < 4; it++) {
        int idx = it * 256 + threadIdx.x;          // 0..1023
        int u   = u0 + (idx >> 5);
        int ch  = (idx & 31) * 8;
        int tok = x[(u & 63) * SEQ + (u >> 6)];
        bf16x8 v;
        if (isbf) {
            v = *(const bf16x8*)((const short*)emb + (size_t)tok * EMB + ch);
        } else {
            const float* src = (const float*)emb + (size_t)tok * EMB + ch;
            #pragma unroll
            for (int j = 0; j < 8; j++) v[j] = f2bf(src[j]);
        }
        *(bf16x8*)(eseq + (size_t)u * EMB + ch) = v;
    }
}

// ---------------------------------------------------------------------------
// K2: intra-XCD persistent scan. 32 participant wgs (one XCD); wg slot s owns
// h cols [16s,16s+16) == gate rows q*512 + 16s + j (q=0..3, j=0..15).
// LDS Ws row n (q=n>>4, j=n&15): cols [0,512)=W_hh, [512,768)=W_ih.
// ---------------------------------------------------------------------------
__global__ __launch_bounds__(256) void k2_lstm(
    const void* __restrict__ w_hh, const void* __restrict__ w_ih,
    const void* __restrict__ b_ih, const void* __restrict__ b_hh,
    const void* __restrict__ emb, const short* __restrict__ eseq,
    short* __restrict__ hbuf, int* __restrict__ sync)
{
    __shared__ short Ws[GROWS][WSROW];   // 99.3 KB
    __shared__ float gates[2][64][68];   // 34.8 KB, double-buffered
    __shared__ float biasl[GROWS];
    __shared__ int   sh_slot;

    const int t = threadIdx.x;

    // ---- XCD leader claim (pigeonhole: with 256 co-resident wgs, some XCD
    // reaches NPART claims; its first NPART claimants persist, rest exit) ----
    if (t == 0) {
        unsigned xcd;
        asm volatile("s_getreg_b32 %0, hwreg(HW_REG_XCC_ID)" : "=s"(xcd));
        xcd &= 7u;
        int c = atomicAdd(&sync[8 + xcd], 1);
        if (c == NPART - 1) atomicCAS(&sync[0], 0, (int)xcd + 1);
        int L;
        while ((L = atomicAdd(&sync[0], 0)) == 0)
            __builtin_amdgcn_s_sleep(8);
        sh_slot = (L == (int)xcd + 1 && c < NPART) ? c : -1;
    }
    __syncthreads();
    const int g = sh_slot;
    if (g < 0) return;

    const bool isbf = detect_bf16(emb);
    const int lane = t & 63;
    const int w    = t >> 6;
    const int col  = lane & 15;
    const int quad = lane >> 4;
    int* cnt = sync + 64;

    // ---- one-time staging: W_hh (64x512) + W_ih (64x256) slices ----
    #pragma unroll
    for (int it = 0; it < 16; it++) {
        int idx = it * 256 + t;
        int n = idx >> 6, ch = (idx & 63) * 8;
        int grow = (n >> 4) * HID + g * WCOLS + (n & 15);
        bf16x8 v;
        if (isbf) {
            v = *(const bf16x8*)((const short*)w_hh + (size_t)grow * HID + ch);
        } else {
            const float* src = (const float*)w_hh + (size_t)grow * HID + ch;
            #pragma unroll
            for (int j = 0; j < 8; j++) v[j] = f2bf(src[j]);
        }
        *(bf16x8*)&Ws[n][ch] = v;
    }
    #pragma unroll
    for (int it = 0; it < 8; it++) {
        int idx = it * 256 + t;
        int n = idx >> 5, ch = (idx & 31) * 8;
        int grow = (n >> 4) * HID + g * WCOLS + (n & 15);
        bf16x8 v;
        if (isbf) {
            v = *(const bf16x8*)((const short*)w_ih + (size_t)grow * EMB + ch);
        } else {
            const float* src = (const float*)w_ih + (size_t)grow * EMB + ch;
            #pragma unroll
            for (int j = 0; j < 8; j++) v[j] = f2bf(src[j]);
        }
        *(bf16x8*)&Ws[n][HID + ch] = v;
    }
    if (t < GROWS) {
        int grow = (t >> 4) * HID + g * WCOLS + (t & 15);
        biasl[t] = rd(b_ih, grow, isbf) + rd(b_hh, grow, isbf);
    }
    __syncthreads();

    // per-thread epilogue mapping: m = t>>2 (batch row), cols jj..jj+3
    const int m  = t >> 2;
    const int jj = (t & 3) * 4;
    float bI[4], bF[4], bG[4], bO[4], cre[4];
    #pragma unroll
    for (int d = 0; d < 4; d++) {
        bI[d] = biasl[jj + d];
        bF[d] = biasl[16 + jj + d];
        bG[d] = biasl[32 + jj + d];
        bO[d] = biasl[48 + jj + d];
        cre[d] = 0.f;
    }

    // ---- scan ----
    for (int step = 0; step < SEQ; step++) {
        // e-frags first (independent of the handshake — overlaps producers)
        bf16x8 afr[24];
        {
            const short* erow = eseq
                + ((size_t)step * BATCH + (w * 16 + col)) * EMB + quad * 8;
            #pragma unroll
            for (int kk = 0; kk < 8; kk++)
                afr[16 + kk] = *(const bf16x8*)(erow + kk * 32);
        }
        if (step > 0) {
            if (t == 0) {
                while (atomicAdd(&cnt[step], 0) < NPART)   // RMW-as-load: fresh
                    __builtin_amdgcn_s_sleep(1);
            }
            __syncthreads();   // also a compiler memory barrier: no load hoist
        }
        // h-frags: plain loads. Fresh by first-touch (this slab never read
        // before) + intra-XCD L2 coherence with producers' plain stores.
        {
            const short* hrow = hbuf + (size_t)step * (BATCH * HID)
                              + (w * 16 + col) * HID + quad * 8;
            #pragma unroll
            for (int kk = 0; kk < 16; kk++)
                afr[kk] = *(const bf16x8*)(hrow + kk * 32);
        }

        floatx4 acc[4];
        #pragma unroll
        for (int nt = 0; nt < 4; nt++) acc[nt] = (floatx4){0.f, 0.f, 0.f, 0.f};
        #pragma unroll
        for (int kk = 0; kk < 24; kk++) {
            bf16x8 a = afr[kk];
            #pragma unroll
            for (int nt = 0; nt < 4; nt++) {
                bf16x8 b = *(bf16x8*)&Ws[nt * 16 + col][kk * 32 + quad * 8];
                acc[nt] = __builtin_amdgcn_mfma_f32_16x16x32_bf16(a, b, acc[nt], 0, 0, 0);
            }
        }
        const int buf = step & 1;
        #pragma unroll
        for (int nt = 0; nt < 4; nt++)
            #pragma unroll
            for (int r = 0; r < 4; r++)
                gates[buf][w * 16 + quad * 4 + r][nt * 16 + col] = acc[nt][r];
        __syncthreads();

        // epilogue: 4 cells per thread; one 8B plain store
        {
            float hv[4];
            #pragma unroll
            for (int d = 0; d < 4; d++) {
                float iv = sigm(gates[buf][m][jj + d]      + bI[d]);
                float fv = sigm(gates[buf][m][16 + jj + d] + bF[d]);
                float gv = tanh_fast(gates[buf][m][32 + jj + d] + bG[d]);
                float ov = sigm(gates[buf][m][48 + jj + d] + bO[d]);
                cre[d] = fv * cre[d] + iv * gv;
                hv[d]  = ov * tanh_fast(cre[d]);
            }
            union { unsigned long long q; short s[4]; } pk;
            #pragma unroll
            for (int d = 0; d < 4; d++) pk.s[d] = f2bf(hv[d]);
            *(unsigned long long*)(hbuf + (size_t)(step + 1) * (BATCH * HID)
                                   + (size_t)m * HID + g * WCOLS + jj) = pk.q;
        }
        __syncthreads();   // vmcnt-drain: all 256 h-stores in L2 before publish
        if (t == 0)
            atomicAdd(&cnt[step + 1], 1);
    }
}

// ---------------------------------------------------------------------------
// K3: logits = h_seq * W_fc^T + b_fc -> log_softmax(18). One token per thread.
// ---------------------------------------------------------------------------
__global__ __launch_bounds__(256) void k3_logits(
    const short* __restrict__ hbuf, const void* __restrict__ w_fc,
    const void* __restrict__ b_fc, const void* __restrict__ emb,
    void* __restrict__ out)
{
    __shared__ float Wf[NOUT][516];
    const bool isbf = detect_bf16(emb);
    const int t = threadIdx.x;
    for (int idx = t; idx < NOUT * 64; idx += 256) {
        int o = idx >> 6, ch = (idx & 63) * 8;
        #pragma unroll
        for (int j = 0; j < 8; j++)
            Wf[o][ch + j] = rd(w_fc, o * HID + ch + j, isbf);
    }
    __syncthreads();

    int u = blockIdx.x * 256 + t;              // u = s*64+b
    const short* hp = hbuf + (size_t)(u + BATCH) * HID;

    float acc[NOUT];
    #pragma unroll
    for (int o = 0; o < NOUT; o++) acc[o] = rd(b_fc, o, isbf);

    for (int ch = 0; ch < HID; ch += 8) {
        bf16x8 h8 = *(const bf16x8*)(hp + ch);
        float hf[8];
        #pragma unroll
        for (int j = 0; j < 8; j++) hf[j] = bf2f(h8[j]);
        #pragma unroll
        for (int o = 0; o < NOUT; o++) {
            floatx4 wa = *(const floatx4*)&Wf[o][ch];
            floatx4 wb = *(const floatx4*)&Wf[o][ch + 4];
            acc[o] += hf[0] * wa[0] + hf[1] * wa[1] + hf[2] * wa[2] + hf[3] * wa[3]
                    + hf[4] * wb[0] + hf[5] * wb[1] + hf[6] * wb[2] + hf[7] * wb[3];
        }
    }

    float mx = acc[0];
    #pragma unroll
    for (int o = 1; o < NOUT; o++) mx = fmaxf(mx, acc[o]);
    float s = 0.f;
    #pragma unroll
    for (int o = 0; o < NOUT; o++) s += __expf(acc[o] - mx);
    float lse = mx + __logf(s);

    int b = u & 63, sq = u >> 6;
    size_t base = (size_t)b * (SEQ * NOUT) + (size_t)sq * NOUT;
    if (isbf) {
        short* op = (short*)out + base;
        #pragma unroll
        for (int o = 0; o < NOUT; o++) op[o] = f2bf(acc[o] - lse);
    } else {
        float* op = (float*)out + base;
        #pragma unroll
        for (int o = 0; o < NOUT; o++) op[o] = acc[o] - lse;
    }
}

// ---------------------------------------------------------------------------
extern "C" void kernel_launch(void* const* d_in, const int* in_sizes, int n_in,
                              void* d_out, int out_size, void* d_ws, size_t ws_size,
                              hipStream_t stream) {
    const int*  x   = (const int*)d_in[0];
    const void* emb = d_in[1];
    const void* wih = d_in[2];
    const void* whh = d_in[3];
    const void* bih = d_in[4];
    const void* bhh = d_in[5];
    const void* wfc = d_in[6];
    const void* bfc = d_in[7];

    char*  ws   = (char*)d_ws;
    int*   sync = (int*)ws;
    short* hbuf = (short*)(ws + 4096);
    short* eseq = (short*)(ws + 4096 + (size_t)(SEQ + 1) * BATCH * HID * 2);

    (void)hipMemsetAsync(sync, 0, 4096, stream);                    // claim+cnt
    (void)hipMemsetAsync(hbuf, 0, (size_t)BATCH * HID * 2, stream); // h_0 = 0

    k0_gather<<<1024, 256, 0, stream>>>(x, emb, eseq);
    k2_lstm<<<256, 256, 0, stream>>>(whh, wih, bih, bhh, emb, eseq, hbuf, sync);
    k3_logits<<<128, 256, 0, stream>>>(hbuf, wfc, bfc, emb, d_out);
}

// Round 10
// 2945.603 us; speedup vs baseline: 1.7948x; 1.0915x over previous
//
#include <hip/hip_runtime.h>
#include <stdint.h>

// LSTMClassifier on MI355X — round 10: intra-XCD scan, WEIGHTS IN REGISTERS.
// Round 9 fixed the fabric (FETCH 493->28 MB) but stalled on LDS: each wave
// re-read the whole 64x768 W slice from LDS every step (393 KB/step/CU,
// +2.4x bank conflicts) at 1 wave/SIMD. W is step-invariant -> hold each
// wave's B-fragments in 384 VGPRs (512-VGPR budget at 1 wave/SIMD), delete
// Ws AND the gates-LDS round trip (acc[nt] already holds gate nt for j=col
// per thread). K-loop: A-frags streamed from L2 in 8-frag windows, e-part
// MFMAs first to hide h-load latency. LDS usage ~0.
//
// Workspace (50.5 MiB):
//   [0,4096)        int sync[1024]: [0]=leader, [8..16)=claim, [64..)=cnt
//   [4096,+33.6MB)  bf16 h_buf[513][64][512]   (h_buf[0] memset 0)
//   [+,  +16.8MB)   bf16 e_seq[32768][256]

#define EMB   256
#define HID   512
#define NOUT  18
#define BATCH 64
#define SEQ   512
#define NPART 32     // scan workgroups = CUs on one XCD
#define WCOLS 16     // h-cols per wg (512/32)

typedef __attribute__((ext_vector_type(8))) short bf16x8;
typedef __attribute__((ext_vector_type(4))) float floatx4;

__device__ inline float bf2f(short u) {
    union { float f; uint32_t i; } v;
    v.i = ((uint32_t)(uint16_t)u) << 16;
    return v.f;
}
__device__ inline short f2bf(float f) {
    union { float f; uint32_t i; } v; v.f = f;
    uint32_t r = v.i + 0x7fffu + ((v.i >> 16) & 1u);   // RNE
    return (short)(r >> 16);
}
__device__ inline float sigm(float x) { return 1.f / (1.f + __expf(-x)); }
__device__ inline float tanh_fast(float x) {
    float xc = fminf(fmaxf(x, -15.f), 15.f);
    float e  = __expf(2.f * xc);
    return (e - 1.f) / (e + 1.f);
}

// Detect packed-bf16 vs fp32 float tensors (verified round 4 — keep).
__device__ inline bool detect_bf16(const void* emb_raw) {
    const uint32_t* w = (const uint32_t*)emb_raw;
    int votes = 0;
    #pragma unroll
    for (int i = 0; i < 8; i++) {
        uint32_t e = (w[i] >> 7) & 0xFFu;
        votes += (e >= 110u && e <= 135u) ? 1 : 0;
    }
    return votes >= 6;
}
__device__ inline float rd(const void* p, int idx, bool isbf) {
    return isbf ? bf2f(((const short*)p)[idx]) : ((const float*)p)[idx];
}

// load one 8-element bf16 fragment from a maybe-fp32 weight row
__device__ inline bf16x8 ldfrag(const void* base, size_t off, bool isbf) {
    if (isbf) return *(const bf16x8*)((const short*)base + off);
    const float* s = (const float*)base + off;
    bf16x8 v;
    #pragma unroll
    for (int j = 0; j < 8; j++) v[j] = f2bf(s[j]);
    return v;
}

// ---------------------------------------------------------------------------
// K0: e_seq[u][k] = emb[x[u&63][u>>6]][k] (bf16 out), u = s*64+b.
// ---------------------------------------------------------------------------
__global__ __launch_bounds__(256) void k0_gather(
    const int* __restrict__ x, const void* __restrict__ emb,
    short* __restrict__ eseq)
{
    const bool isbf = detect_bf16(emb);
    const int u0 = blockIdx.x * 32;
    #pragma unroll
    for (int it = 0; it < 4; it++) {
        int idx = it * 256 + threadIdx.x;          // 0..1023
        int u   = u0 + (idx >> 5);
        int ch  = (idx & 31) * 8;
        int tok = x[(u & 63) * SEQ + (u >> 6)];
        bf16x8 v;
        if (isbf) {
            v = *(const bf16x8*)((const short*)emb + (size_t)tok * EMB + ch);
        } else {
            const float* src = (const float*)emb + (size_t)tok * EMB + ch;
            #pragma unroll
            for (int j = 0; j < 8; j++) v[j] = f2bf(src[j]);
        }
        *(bf16x8*)(eseq + (size_t)u * EMB + ch) = v;
    }
}

// ---------------------------------------------------------------------------
// K2: intra-XCD persistent scan, register-resident weights. 32 wgs; wg slot g
// owns h cols [16g,16g+16). Wave w handles batch rows [16w,16w+16); per-lane
// acc[nt][r] = gate nt (i,f,g,o) of cell (m = 16w+quad*4+r, j = col).
// ---------------------------------------------------------------------------
__global__ __launch_bounds__(256, 1) void k2_lstm(
    const void* __restrict__ w_hh, const void* __restrict__ w_ih,
    const void* __restrict__ b_ih, const void* __restrict__ b_hh,
    const void* __restrict__ emb, const short* __restrict__ eseq,
    short* __restrict__ hbuf, int* __restrict__ sync)
{
    __shared__ float biasl[64];
    __shared__ int   sh_slot;

    const int t = threadIdx.x;

    // ---- XCD leader claim (round-9 verified) ----
    if (t == 0) {
        unsigned xcd;
        asm volatile("s_getreg_b32 %0, hwreg(HW_REG_XCC_ID)" : "=s"(xcd));
        xcd &= 7u;
        int c = atomicAdd(&sync[8 + xcd], 1);
        if (c == NPART - 1) atomicCAS(&sync[0], 0, (int)xcd + 1);
        int L;
        while ((L = atomicAdd(&sync[0], 0)) == 0)
            __builtin_amdgcn_s_sleep(8);
        sh_slot = (L == (int)xcd + 1 && c < NPART) ? c : -1;
    }
    __syncthreads();
    const int g = sh_slot;
    if (g < 0) return;

    const bool isbf = detect_bf16(emb);
    const int lane = t & 63;
    const int w    = t >> 6;
    const int col  = lane & 15;
    const int quad = lane >> 4;
    int* cnt = sync + 64;

    // ---- B fragments to registers: breg[nt][kk], 96 x bf16x8 = 384 VGPRs.
    // Lane's B row for tile nt: gate q=nt, j=col -> W row nt*512 + g*16 + col.
    bf16x8 breg[4][24];
    #pragma unroll
    for (int nt = 0; nt < 4; nt++) {
        const size_t grow = (size_t)(nt * HID + g * WCOLS + col);
        #pragma unroll
        for (int kk = 0; kk < 16; kk++)
            breg[nt][kk] = ldfrag(w_hh, grow * HID + kk * 32 + quad * 8, isbf);
        #pragma unroll
        for (int kk = 0; kk < 8; kk++)
            breg[nt][16 + kk] = ldfrag(w_ih, grow * EMB + kk * 32 + quad * 8, isbf);
    }
    if (t < 64) {
        int grow = (t >> 4) * HID + g * WCOLS + (t & 15);
        biasl[t] = rd(b_ih, grow, isbf) + rd(b_hh, grow, isbf);
    }
    __syncthreads();
    const float bI = biasl[col],      bF = biasl[16 + col];
    const float bG = biasl[32 + col], bO = biasl[48 + col];

    float cre[4] = {0.f, 0.f, 0.f, 0.f};

    const short* eptr = eseq + (size_t)(w * 16 + col) * EMB + quad * 8;
    const short* hrd  = hbuf + (size_t)(w * 16 + col) * HID + quad * 8;
    short*       hwr  = hbuf + (size_t)(BATCH * HID)
                      + (size_t)(w * 16 + quad * 4) * HID + g * WCOLS + col;

    // ---- scan ----
    for (int step = 0; step < SEQ; step++) {
        // e A-frags: independent of handshake — issue before the poll
        bf16x8 ae[8];
        #pragma unroll
        for (int kk = 0; kk < 8; kk++)
            ae[kk] = *(const bf16x8*)(eptr + kk * 32);

        if (step > 0) {
            if (t == 0) {
                while (atomicAdd(&cnt[step], 0) < NPART)   // RMW-as-load
                    __builtin_amdgcn_s_sleep(1);
            }
            __syncthreads();
        }

        floatx4 a0 = (floatx4){0.f,0.f,0.f,0.f}, a1 = a0, a2 = a0, a3 = a0;

        // issue first h window, then burn e-MFMAs while it flies
        bf16x8 ah[8];
        #pragma unroll
        for (int kk = 0; kk < 8; kk++)
            ah[kk] = *(const bf16x8*)(hrd + kk * 32);
        #pragma unroll
        for (int kk = 0; kk < 8; kk++) {
            a0 = __builtin_amdgcn_mfma_f32_16x16x32_bf16(ae[kk], breg[0][16+kk], a0, 0,0,0);
            a1 = __builtin_amdgcn_mfma_f32_16x16x32_bf16(ae[kk], breg[1][16+kk], a1, 0,0,0);
            a2 = __builtin_amdgcn_mfma_f32_16x16x32_bf16(ae[kk], breg[2][16+kk], a2, 0,0,0);
            a3 = __builtin_amdgcn_mfma_f32_16x16x32_bf16(ae[kk], breg[3][16+kk], a3, 0,0,0);
        }
        // second h window into the (consumed) e buffer
        #pragma unroll
        for (int kk = 0; kk < 8; kk++)
            ae[kk] = *(const bf16x8*)(hrd + (8 + kk) * 32);
        #pragma unroll
        for (int kk = 0; kk < 8; kk++) {
            a0 = __builtin_amdgcn_mfma_f32_16x16x32_bf16(ah[kk], breg[0][kk], a0, 0,0,0);
            a1 = __builtin_amdgcn_mfma_f32_16x16x32_bf16(ah[kk], breg[1][kk], a1, 0,0,0);
            a2 = __builtin_amdgcn_mfma_f32_16x16x32_bf16(ah[kk], breg[2][kk], a2, 0,0,0);
            a3 = __builtin_amdgcn_mfma_f32_16x16x32_bf16(ah[kk], breg[3][kk], a3, 0,0,0);
        }
        #pragma unroll
        for (int kk = 0; kk < 8; kk++) {
            a0 = __builtin_amdgcn_mfma_f32_16x16x32_bf16(ae[kk], breg[0][8+kk], a0, 0,0,0);
            a1 = __builtin_amdgcn_mfma_f32_16x16x32_bf16(ae[kk], breg[1][8+kk], a1, 0,0,0);
            a2 = __builtin_amdgcn_mfma_f32_16x16x32_bf16(ae[kk], breg[2][8+kk], a2, 0,0,0);
            a3 = __builtin_amdgcn_mfma_f32_16x16x32_bf16(ae[kk], breg[3][8+kk], a3, 0,0,0);
        }

        // in-register epilogue: a0..a3 = gates i,f,g,o of cells (m=quad*4+r+16w, j=col)
        #pragma unroll
        for (int r = 0; r < 4; r++) {
            float iv = sigm(a0[r] + bI);
            float fv = sigm(a1[r] + bF);
            float gv = tanh_fast(a2[r] + bG);
            float ov = sigm(a3[r] + bO);
            cre[r] = fv * cre[r] + iv * gv;
            float h = ov * tanh_fast(cre[r]);
            hwr[(size_t)r * HID] = f2bf(h);
        }
        __syncthreads();   // vmcnt-drain: all h-stores in XCD L2 before publish
        if (t == 0)
            atomicAdd(&cnt[step + 1], 1);

        eptr += (size_t)BATCH * EMB;
        hrd  += (size_t)BATCH * HID;
        hwr  += (size_t)BATCH * HID;
    }
}

// ---------------------------------------------------------------------------
// K3: logits = h_seq * W_fc^T + b_fc -> log_softmax(18). One token per thread.
// ---------------------------------------------------------------------------
__global__ __launch_bounds__(256) void k3_logits(
    const short* __restrict__ hbuf, const void* __restrict__ w_fc,
    const void* __restrict__ b_fc, const void* __restrict__ emb,
    void* __restrict__ out)
{
    __shared__ float Wf[NOUT][516];
    const bool isbf = detect_bf16(emb);
    const int t = threadIdx.x;
    for (int idx = t; idx < NOUT * 64; idx += 256) {
        int o = idx >> 6, ch = (idx & 63) * 8;
        #pragma unroll
        for (int j = 0; j < 8; j++)
            Wf[o][ch + j] = rd(w_fc, o * HID + ch + j, isbf);
    }
    __syncthreads();

    int u = blockIdx.x * 256 + t;              // u = s*64+b
    const short* hp = hbuf + (size_t)(u + BATCH) * HID;

    float acc[NOUT];
    #pragma unroll
    for (int o = 0; o < NOUT; o++) acc[o] = rd(b_fc, o, isbf);

    for (int ch = 0; ch < HID; ch += 8) {
        bf16x8 h8 = *(const bf16x8*)(hp + ch);
        float hf[8];
        #pragma unroll
        for (int j = 0; j < 8; j++) hf[j] = bf2f(h8[j]);
        #pragma unroll
        for (int o = 0; o < NOUT; o++) {
            floatx4 wa = *(const floatx4*)&Wf[o][ch];
            floatx4 wb = *(const floatx4*)&Wf[o][ch + 4];
            acc[o] += hf[0] * wa[0] + hf[1] * wa[1] + hf[2] * wa[2] + hf[3] * wa[3]
                    + hf[4] * wb[0] + hf[5] * wb[1] + hf[6] * wb[2] + hf[7] * wb[3];
        }
    }

    float mx = acc[0];
    #pragma unroll
    for (int o = 1; o < NOUT; o++) mx = fmaxf(mx, acc[o]);
    float s = 0.f;
    #pragma unroll
    for (int o = 0; o < NOUT; o++) s += __expf(acc[o] - mx);
    float lse = mx + __logf(s);

    int b = u & 63, sq = u >> 6;
    size_t base = (size_t)b * (SEQ * NOUT) + (size_t)sq * NOUT;
    if (isbf) {
        short* op = (short*)out + base;
        #pragma unroll
        for (int o = 0; o < NOUT; o++) op[o] = f2bf(acc[o] - lse);
    } else {
        float* op = (float*)out + base;
        #pragma unroll
        for (int o = 0; o < NOUT; o++) op[o] = acc[o] - lse;
    }
}

// ---------------------------------------------------------------------------
extern "C" void kernel_launch(void* const* d_in, const int* in_sizes, int n_in,
                              void* d_out, int out_size, void* d_ws, size_t ws_size,
                              hipStream_t stream) {
    const int*  x   = (const int*)d_in[0];
    const void* emb = d_in[1];
    const void* wih = d_in[2];
    const void* whh = d_in[3];
    const void* bih = d_in[4];
    const void* bhh = d_in[5];
    const void* wfc = d_in[6];
    const void* bfc = d_in[7];

    char*  ws   = (char*)d_ws;
    int*   sync = (int*)ws;
    short* hbuf = (short*)(ws + 4096);
    short* eseq = (short*)(ws + 4096 + (size_t)(SEQ + 1) * BATCH * HID * 2);

    (void)hipMemsetAsync(sync, 0, 4096, stream);                    // claim+cnt
    (void)hipMemsetAsync(hbuf, 0, (size_t)BATCH * HID * 2, stream); // h_0 = 0

    k0_gather<<<1024, 256, 0, stream>>>(x, emb, eseq);
    k2_lstm<<<256, 256, 0, stream>>>(whh, wih, bih, bhh, emb, eseq, hbuf, sync);
    k3_logits<<<128, 256, 0, stream>>>(hbuf, wfc, bfc, emb, d_out);
}

// Round 12
// 2879.654 us; speedup vs baseline: 1.8359x; 1.0229x over previous
//
#include <hip/hip_runtime.h>
#include <stdint.h>

// LSTMClassifier on MI355X — round 12: RMW-free flag sync, hang-proofed.
// Round 11 (plain-store publish + sc0-load poll) died with an opaque infra
// error — possibly a GPU hang if plain-store -> sc0-load visibility fails.
// Identical design, but every spin loop now has a bounded fast phase and a
// guaranteed-progress fallback (atomicAdd RMW at the device coherent point,
// which always observes completed plain stores). Deadlock impossible.
//
// Workspace (50.6 MiB):
//   [0,4096)          int sync[]: [0]=leader, [8..16)=claim counters
//   [4096, +131.3KB)  int flags[513][64]     (memset 0 per launch)
//   [+, +33.6MB)      bf16 h_buf[513][64][512]  (h_buf[0] memset 0)
//   [+, +16.8MB)      bf16 e_seq[32768][256]

#define EMB   256
#define HID   512
#define NOUT  18
#define BATCH 64
#define SEQ   512
#define NPART 32     // scan workgroups = CUs on one XCD
#define WCOLS 16     // h-cols per wg (512/32)

typedef __attribute__((ext_vector_type(8))) short bf16x8;
typedef __attribute__((ext_vector_type(4))) float floatx4;

__device__ inline float bf2f(short u) {
    union { float f; uint32_t i; } v;
    v.i = ((uint32_t)(uint16_t)u) << 16;
    return v.f;
}
__device__ inline short f2bf(float f) {
    union { float f; uint32_t i; } v; v.f = f;
    uint32_t r = v.i + 0x7fffu + ((v.i >> 16) & 1u);   // RNE
    return (short)(r >> 16);
}
__device__ inline float sigm(float x) { return 1.f / (1.f + __expf(-x)); }
__device__ inline float tanh_fast(float x) {
    float xc = fminf(fmaxf(x, -15.f), 15.f);
    float e  = __expf(2.f * xc);
    return (e - 1.f) / (e + 1.f);
}

// L1-bypassing load (sc0): served by this XCD's L2 (intra-XCD coherence point).
__device__ inline int load_l2(const int* p) {
    int v;
    asm volatile("global_load_dword %0, %1, off sc0\n\t"
                 "s_waitcnt vmcnt(0)"
                 : "=v"(v) : "v"(p) : "memory");
    return v;
}

// Detect packed-bf16 vs fp32 float tensors (verified round 4 — keep).
__device__ inline bool detect_bf16(const void* emb_raw) {
    const uint32_t* w = (const uint32_t*)emb_raw;
    int votes = 0;
    #pragma unroll
    for (int i = 0; i < 8; i++) {
        uint32_t e = (w[i] >> 7) & 0xFFu;
        votes += (e >= 110u && e <= 135u) ? 1 : 0;
    }
    return votes >= 6;
}
__device__ inline float rd(const void* p, int idx, bool isbf) {
    return isbf ? bf2f(((const short*)p)[idx]) : ((const float*)p)[idx];
}

// load one 8-element bf16 fragment from a maybe-fp32 weight row
__device__ inline bf16x8 ldfrag(const void* base, size_t off, bool isbf) {
    if (isbf) return *(const bf16x8*)((const short*)base + off);
    const float* s = (const float*)base + off;
    bf16x8 v;
    #pragma unroll
    for (int j = 0; j < 8; j++) v[j] = f2bf(s[j]);
    return v;
}

// ---------------------------------------------------------------------------
// K0: e_seq[u][k] = emb[x[u&63][u>>6]][k] (bf16 out), u = s*64+b.
// ---------------------------------------------------------------------------
__global__ __launch_bounds__(256) void k0_gather(
    const int* __restrict__ x, const void* __restrict__ emb,
    short* __restrict__ eseq)
{
    const bool isbf = detect_bf16(emb);
    const int u0 = blockIdx.x * 32;
    #pragma unroll
    for (int it = 0; it < 4; it++) {
        int idx = it * 256 + threadIdx.x;          // 0..1023
        int u   = u0 + (idx >> 5);
        int ch  = (idx & 31) * 8;
        int tok = x[(u & 63) * SEQ + (u >> 6)];
        bf16x8 v;
        if (isbf) {
            v = *(const bf16x8*)((const short*)emb + (size_t)tok * EMB + ch);
        } else {
            const float* src = (const float*)emb + (size_t)tok * EMB + ch;
            #pragma unroll
            for (int j = 0; j < 8; j++) v[j] = f2bf(src[j]);
        }
        *(bf16x8*)(eseq + (size_t)u * EMB + ch) = v;
    }
}

// ---------------------------------------------------------------------------
// K2: intra-XCD persistent scan, register weights, RMW-free flag sync with
// guaranteed-progress fallback. 32 wgs; slot g owns h cols [16g,16g+16).
// ---------------------------------------------------------------------------
__global__ __launch_bounds__(256, 1) void k2_lstm(
    const void* __restrict__ w_hh, const void* __restrict__ w_ih,
    const void* __restrict__ b_ih, const void* __restrict__ b_hh,
    const void* __restrict__ emb, const short* __restrict__ eseq,
    short* __restrict__ hbuf, int* __restrict__ sync, int* __restrict__ flags)
{
    __shared__ float biasl[64];
    __shared__ int   sh_slot;

    const int t = threadIdx.x;

    // ---- XCD leader claim (round-9/10 verified; startup only).
    // Pigeonhole: 8*31 = 248 < 256 grid => some XCD always reaches NPART. ----
    if (t == 0) {
        unsigned xcd;
        asm volatile("s_getreg_b32 %0, hwreg(HW_REG_XCC_ID)" : "=s"(xcd));
        xcd &= 7u;
        int c = atomicAdd(&sync[8 + xcd], 1);
        if (c == NPART - 1) atomicCAS(&sync[0], 0, (int)xcd + 1);
        int L;
        while ((L = atomicAdd(&sync[0], 0)) == 0)
            __builtin_amdgcn_s_sleep(8);
        sh_slot = (L == (int)xcd + 1 && c < NPART) ? c : -1;
    }
    __syncthreads();
    const int g = sh_slot;
    if (g < 0) return;

    const bool isbf = detect_bf16(emb);
    const int lane = t & 63;
    const int w    = t >> 6;
    const int col  = lane & 15;
    const int quad = lane >> 4;

    // ---- B fragments to registers: breg[nt][kk], 96 x bf16x8 ----
    bf16x8 breg[4][24];
    #pragma unroll
    for (int nt = 0; nt < 4; nt++) {
        const size_t grow = (size_t)(nt * HID + g * WCOLS + col);
        #pragma unroll
        for (int kk = 0; kk < 16; kk++)
            breg[nt][kk] = ldfrag(w_hh, grow * HID + kk * 32 + quad * 8, isbf);
        #pragma unroll
        for (int kk = 0; kk < 8; kk++)
            breg[nt][16 + kk] = ldfrag(w_ih, grow * EMB + kk * 32 + quad * 8, isbf);
    }
    if (t < 64) {
        int grow = (t >> 4) * HID + g * WCOLS + (t & 15);
        biasl[t] = rd(b_ih, grow, isbf) + rd(b_hh, grow, isbf);
    }
    __syncthreads();
    const float bI = biasl[col],      bF = biasl[16 + col];
    const float bG = biasl[32 + col], bO = biasl[48 + col];

    float cre[4] = {0.f, 0.f, 0.f, 0.f};

    const short* eptr = eseq + (size_t)(w * 16 + col) * EMB + quad * 8;
    const short* hrd  = hbuf + (size_t)(w * 16 + col) * HID + quad * 8;
    short*       hwr  = hbuf + (size_t)(BATCH * HID)
                      + (size_t)(w * 16 + quad * 4) * HID + g * WCOLS + col;

    // ---- scan ----
    for (int step = 0; step < SEQ; step++) {
        // e A-frags: independent of the handshake — issue before the poll
        bf16x8 ae[8];
        #pragma unroll
        for (int kk = 0; kk < 8; kk++)
            ae[kk] = *(const bf16x8*)(eptr + kk * 32);

        // wait: each wave's lanes 0..31 poll the 32 per-producer flags in
        // parallel (sc0, local L2, no RMW). Bounded; falls back to a coherent
        // RMW read which ALWAYS observes completed plain stores -> no hang.
        if (step > 0 && lane < NPART) {
            int* fp = flags + (size_t)step * 64 + lane;
            int iters = 0;
            while (load_l2(fp) == 0) {
                if (++iters > 4096) {
                    while (atomicAdd(fp, 0) == 0)
                        __builtin_amdgcn_s_sleep(8);
                    break;
                }
                __builtin_amdgcn_s_sleep(1);
            }
        }

        floatx4 a0 = (floatx4){0.f,0.f,0.f,0.f}, a1 = a0, a2 = a0, a3 = a0;

        // first h window; e-MFMAs burn while it flies
        bf16x8 ah[8];
        #pragma unroll
        for (int kk = 0; kk < 8; kk++)
            ah[kk] = *(const bf16x8*)(hrd + kk * 32);
        #pragma unroll
        for (int kk = 0; kk < 8; kk++) {
            a0 = __builtin_amdgcn_mfma_f32_16x16x32_bf16(ae[kk], breg[0][16+kk], a0, 0,0,0);
            a1 = __builtin_amdgcn_mfma_f32_16x16x32_bf16(ae[kk], breg[1][16+kk], a1, 0,0,0);
            a2 = __builtin_amdgcn_mfma_f32_16x16x32_bf16(ae[kk], breg[2][16+kk], a2, 0,0,0);
            a3 = __builtin_amdgcn_mfma_f32_16x16x32_bf16(ae[kk], breg[3][16+kk], a3, 0,0,0);
        }
        #pragma unroll
        for (int kk = 0; kk < 8; kk++)
            ae[kk] = *(const bf16x8*)(hrd + (8 + kk) * 32);
        #pragma unroll
        for (int kk = 0; kk < 8; kk++) {
            a0 = __builtin_amdgcn_mfma_f32_16x16x32_bf16(ah[kk], breg[0][kk], a0, 0,0,0);
            a1 = __builtin_amdgcn_mfma_f32_16x16x32_bf16(ah[kk], breg[1][kk], a1, 0,0,0);
            a2 = __builtin_amdgcn_mfma_f32_16x16x32_bf16(ah[kk], breg[2][kk], a2, 0,0,0);
            a3 = __builtin_amdgcn_mfma_f32_16x16x32_bf16(ah[kk], breg[3][kk], a3, 0,0,0);
        }
        #pragma unroll
        for (int kk = 0; kk < 8; kk++) {
            a0 = __builtin_amdgcn_mfma_f32_16x16x32_bf16(ae[kk], breg[0][8+kk], a0, 0,0,0);
            a1 = __builtin_amdgcn_mfma_f32_16x16x32_bf16(ae[kk], breg[1][8+kk], a1, 0,0,0);
            a2 = __builtin_amdgcn_mfma_f32_16x16x32_bf16(ae[kk], breg[2][8+kk], a2, 0,0,0);
            a3 = __builtin_amdgcn_mfma_f32_16x16x32_bf16(ae[kk], breg[3][8+kk], a3, 0,0,0);
        }

        // in-register epilogue
        #pragma unroll
        for (int r = 0; r < 4; r++) {
            float iv = sigm(a0[r] + bI);
            float fv = sigm(a1[r] + bF);
            float gv = tanh_fast(a2[r] + bG);
            float ov = sigm(a3[r] + bO);
            cre[r] = fv * cre[r] + iv * gv;
            float h = ov * tanh_fast(cre[r]);
            hwr[(size_t)r * HID] = f2bf(h);
        }
        __syncthreads();   // vmcnt-drain: all 256 threads' h-stores in L2
        if (t == 0)
            flags[(size_t)(step + 1) * 64 + g] = 1;   // plain publish -> L2

        eptr += (size_t)BATCH * EMB;
        hrd  += (size_t)BATCH * HID;
        hwr  += (size_t)BATCH * HID;
    }
}

// ---------------------------------------------------------------------------
// K3: logits = h_seq * W_fc^T + b_fc -> log_softmax(18). One token per thread.
// ---------------------------------------------------------------------------
__global__ __launch_bounds__(256) void k3_logits(
    const short* __restrict__ hbuf, const void* __restrict__ w_fc,
    const void* __restrict__ b_fc, const void* __restrict__ emb,
    void* __restrict__ out)
{
    __shared__ float Wf[NOUT][516];
    const bool isbf = detect_bf16(emb);
    const int t = threadIdx.x;
    for (int idx = t; idx < NOUT * 64; idx += 256) {
        int o = idx >> 6, ch = (idx & 63) * 8;
        #pragma unroll
        for (int j = 0; j < 8; j++)
            Wf[o][ch + j] = rd(w_fc, o * HID + ch + j, isbf);
    }
    __syncthreads();

    int u = blockIdx.x * 256 + t;              // u = s*64+b
    const short* hp = hbuf + (size_t)(u + BATCH) * HID;

    float acc[NOUT];
    #pragma unroll
    for (int o = 0; o < NOUT; o++) acc[o] = rd(b_fc, o, isbf);

    for (int ch = 0; ch < HID; ch += 8) {
        bf16x8 h8 = *(const bf16x8*)(hp + ch);
        float hf[8];
        #pragma unroll
        for (int j = 0; j < 8; j++) hf[j] = bf2f(h8[j]);
        #pragma unroll
        for (int o = 0; o < NOUT; o++) {
            floatx4 wa = *(const floatx4*)&Wf[o][ch];
            floatx4 wb = *(const floatx4*)&Wf[o][ch + 4];
            acc[o] += hf[0] * wa[0] + hf[1] * wa[1] + hf[2] * wa[2] + hf[3] * wa[3]
                    + hf[4] * wb[0] + hf[5] * wb[1] + hf[6] * wb[2] + hf[7] * wb[3];
        }
    }

    float mx = acc[0];
    #pragma unroll
    for (int o = 1; o < NOUT; o++) mx = fmaxf(mx, acc[o]);
    float s = 0.f;
    #pragma unroll
    for (int o = 0; o < NOUT; o++) s += __expf(acc[o] - mx);
    float lse = mx + __logf(s);

    int b = u & 63, sq = u >> 6;
    size_t base = (size_t)b * (SEQ * NOUT) + (size_t)sq * NOUT;
    if (isbf) {
        short* op = (short*)out + base;
        #pragma unroll
        for (int o = 0; o < NOUT; o++) op[o] = f2bf(acc[o] - lse);
    } else {
        float* op = (float*)out + base;
        #pragma unroll
        for (int o = 0; o < NOUT; o++) op[o] = acc[o] - lse;
    }
}

// ---------------------------------------------------------------------------
extern "C" void kernel_launch(void* const* d_in, const int* in_sizes, int n_in,
                              void* d_out, int out_size, void* d_ws, size_t ws_size,
                              hipStream_t stream) {
    const int*  x   = (const int*)d_in[0];
    const void* emb = d_in[1];
    const void* wih = d_in[2];
    const void* whh = d_in[3];
    const void* bih = d_in[4];
    const void* bhh = d_in[5];
    const void* wfc = d_in[6];
    const void* bfc = d_in[7];

    char*  ws    = (char*)d_ws;
    int*   sync  = (int*)ws;
    int*   flags = (int*)(ws + 4096);
    const size_t flagsz = (size_t)(SEQ + 1) * 64 * sizeof(int);   // 131.3 KB
    short* hbuf  = (short*)(ws + 4096 + ((flagsz + 255) & ~(size_t)255));
    short* eseq  = (short*)((char*)hbuf + (size_t)(SEQ + 1) * BATCH * HID * 2);

    (void)hipMemsetAsync(sync, 0, 4096, stream);                    // claim
    (void)hipMemsetAsync(flags, 0, flagsz, stream);                 // flags = 0
    (void)hipMemsetAsync(hbuf, 0, (size_t)BATCH * HID * 2, stream); // h_0 = 0

    k0_gather<<<1024, 256, 0, stream>>>(x, emb, eseq);
    k2_lstm<<<256, 256, 0, stream>>>(whh, wih, bih, bhh, emb, eseq,
                                     hbuf, sync, flags);
    k3_logits<<<128, 256, 0, stream>>>(hbuf, wfc, bfc, emb, d_out);
}